// Round 1
// baseline (206.634 us; speedup 1.0000x reference)
//
#include <hip/hip_runtime.h>
#include <hip/hip_bf16.h>

// CrossAttention: B=4, C=256, N=4096, OUT=256, temp=16.
// v9: flash_attn loses the per-interval vmcnt(0) drain.
//  - In-loop __syncthreads() -> s_waitcnt lgkmcnt(0) + raw s_barrier.
//    K/V staging is wave-private (producer pw loads AND consumes K granule
//    pw; consumer pw loads AND consumes V slice pw), so only the ps
//    handoff needs the barrier. Per-wave counted s_waitcnt vmcnt(8)
//    keeps 8 DMAs in flight across the barrier (T3/T4 pattern).
//  - s_setprio(1) around both MFMA clusters (T5: real producer/consumer
//    role-split on every SIMD).
//  - proj/wcvt unchanged from v8 for clean attribution.
// Workspace: qg 8.4MB + kt 8.4MB + vt 8.4MB + wb 384KB.

typedef __attribute__((ext_vector_type(8))) short bf16x8;
typedef __attribute__((ext_vector_type(4))) float f32x4;
typedef __attribute__((ext_vector_type(4))) short short4t;

constexpr int B_ = 4;
constexpr int C_ = 256;
constexpr int N_ = 4096;
constexpr int O_ = 256;
constexpr float INV_TEMP = 1.0f / 16.0f;
constexpr int NIT = 64;   // 64-key blocks per WG (all 4096 keys, SPLIT=1)

__device__ __forceinline__ short f2bf(float f) {
  union { float f; unsigned u; } v; v.f = f;
  unsigned r = v.u + 0x7fffu + ((v.u >> 16) & 1u);   // RNE
  return (short)(r >> 16);
}

// async global->LDS DMA: one call moves 64 lanes x 16B = 1024B (512 shorts)
__device__ __forceinline__ void dma16(const short* g, short* l) {
  __builtin_amdgcn_global_load_lds(
      (const __attribute__((address_space(1))) unsigned int*)g,
      (__attribute__((address_space(3))) unsigned int*)l, 16, 0, 0);
}

// ---------------------------------------------------------------------------
__global__ void wcvt(const float* __restrict__ Wq, const float* __restrict__ Wk,
                     const float* __restrict__ Wv, short* __restrict__ wb) {
  int i = blockIdx.x * 256 + threadIdx.x;        // 0..196607
  int mat = i >> 16, off = i & 65535;
  const float* W = (mat == 0) ? Wq : (mat == 1 ? Wk : Wv);
  wb[i] = f2bf(W[off]);
}

// ---------------------------------------------------------------------------
// Projections. Grid (64, B, 3). Block 256 (4 waves). z: 0=Q, 1=K, 2=V.
// Epilogue: assemble the WG's contiguous 32KB output span in LDS, blast out.
// ---------------------------------------------------------------------------
__global__ __launch_bounds__(256, 2) void qkv_proj(
    const float* __restrict__ x, const float* __restrict__ xx,
    const short* __restrict__ wb,
    short* __restrict__ qg, short* __restrict__ kt, short* __restrict__ vt) {
  const int n0  = blockIdx.x * 64;
  const int b   = blockIdx.y;
  const int mat = blockIdx.z;
  const float* src = (mat == 0) ? x : xx;
  const short* W   = wb + mat * 65536;
  const int tid = threadIdx.x;
  const int w = tid >> 6, lane = tid & 63;
  const int g = lane >> 4, c16 = lane & 15;

  __shared__ __align__(16) short xs[64][264];   // staged tile / out assembly

  {  // transpose staging: coalesced dword loads along n, short4 LDS writes
    const int n = tid & 63, cq = tid >> 6;
    const float* sp = src + (size_t)b * C_ * N_ + n0 + n;
#pragma unroll
    for (int rep = 0; rep < 16; ++rep) {
      int c = rep * 16 + cq * 4;
      short4t s4;
#pragma unroll
      for (int j = 0; j < 4; ++j) s4[j] = f2bf(sp[(size_t)(c + j) * N_]);
      *(short4t*)&xs[n][c] = s4;
    }
  }
  __syncthreads();

  f32x4 acc[4][4];
#pragma unroll
  for (int i = 0; i < 4; ++i)
#pragma unroll
    for (int j = 0; j < 4; ++j) acc[i][j] = (f32x4){0.f, 0.f, 0.f, 0.f};

#pragma unroll
  for (int ko = 0; ko < 8; ++ko) {
    bf16x8 wfr[4], xfr[4];
#pragma unroll
    for (int ot = 0; ot < 4; ++ot)
      wfr[ot] = *(const bf16x8*)&W[(w * 64 + ot * 16 + c16) * C_ + ko * 32 + g * 8];
#pragma unroll
    for (int nt = 0; nt < 4; ++nt)
      xfr[nt] = *(const bf16x8*)&xs[nt * 16 + c16][ko * 32 + g * 8];
    if (mat < 2) {
#pragma unroll
      for (int ot = 0; ot < 4; ++ot)
#pragma unroll
        for (int nt = 0; nt < 4; ++nt)
          acc[ot][nt] = __builtin_amdgcn_mfma_f32_16x16x32_bf16(
              wfr[ot], xfr[nt], acc[ot][nt], 0, 0, 0);
    } else {  // V: swapped operands -> D rows = m, cols = o
#pragma unroll
      for (int mt = 0; mt < 4; ++mt)
#pragma unroll
        for (int ot = 0; ot < 4; ++ot)
          acc[mt][ot] = __builtin_amdgcn_mfma_f32_16x16x32_bf16(
              xfr[mt], wfr[ot], acc[mt][ot], 0, 0, 0);
    }
  }

  __syncthreads();               // xs tile reads done; reuse as out-assembly
  short* ob = &xs[0][0];         // 16384 shorts used

  if (mat == 0) {
#pragma unroll
    for (int ot = 0; ot < 4; ++ot)
#pragma unroll
      for (int nt = 0; nt < 4; ++nt) {
        int f = (nt * 16 + c16) * 256 + w * 64 + ot * 16 + g * 4;
        short4t s;
        s[0] = f2bf(acc[ot][nt][0] * INV_TEMP);
        s[1] = f2bf(acc[ot][nt][1] * INV_TEMP);
        s[2] = f2bf(acc[ot][nt][2] * INV_TEMP);
        s[3] = f2bf(acc[ot][nt][3] * INV_TEMP);
        *(short4t*)&ob[f] = s;
      }
  } else if (mat == 1) {
#pragma unroll
    for (int ot = 0; ot < 4; ++ot)
#pragma unroll
      for (int nt = 0; nt < 4; ++nt) {
        int koo = w * 2 + (ot >> 1);
        int pos = (((ot & 1) * 2 + (g >> 1)) ^ ((c16 >> 1) & 3));
        int f = nt * 4096 + koo * 512 + c16 * 32 + pos * 8 + (g & 1) * 4;
        short4t s;
        s[0] = f2bf(acc[ot][nt][0]);
        s[1] = f2bf(acc[ot][nt][1]);
        s[2] = f2bf(acc[ot][nt][2]);
        s[3] = f2bf(acc[ot][nt][3]);
        *(short4t*)&ob[f] = s;
      }
  } else {  // V: acc[mt][ot], rows m = mt*16+g*4+r, cols o = w*64+ot*16+c16
#pragma unroll
    for (int mt = 0; mt < 4; ++mt)
#pragma unroll
      for (int ot = 0; ot < 4; ++ot) {
        int o = w * 64 + ot * 16 + c16;
        int pos = (mt * 2 + (g >> 1)) ^ (o & 7);
        int f = o * 64 + pos * 8 + (g & 1) * 4;
        short4t s;
        s[0] = f2bf(acc[mt][ot][0]);
        s[1] = f2bf(acc[mt][ot][1]);
        s[2] = f2bf(acc[mt][ot][2]);
        s[3] = f2bf(acc[mt][ot][3]);
        *(short4t*)&ob[f] = s;
      }
  }
  __syncthreads();

  short* dst = (mat == 0) ? qg + ((size_t)b * N_ + n0) * O_
             : (mat == 1) ? kt + (size_t)(b * 256 + (n0 >> 4)) * 4096
                          : vt + (size_t)(b * 64 + (n0 >> 6)) * 16384;
  const uint4* s4 = (const uint4*)ob;
  uint4* d4 = (uint4*)dst;
#pragma unroll
  for (int j = 0; j < 8; ++j) d4[j * 256 + tid] = s4[j * 256 + tid];
}

// ---------------------------------------------------------------------------
// Flash attention, wave-specialized. Grid (8, 32). Block 512 (8 waves).
// b = x>>1 (XCD-pinned), nblk = (x&1)*32 + y, n0 = nblk*64.
// Waves 0-3 producers (16-key granules), 4-7 consumers (64-o slices).
// LDS: kb 2x32KB + vb 2x32KB + ps 2x9.2KB + lsum = 147.4KB -> 1 WG/CU.
// v9 sync contract:
//  - one raw s_barrier per interval, preceded by lgkmcnt(0) only
//    (ps handoff + LDS WAR safety). NO vmcnt drain at the barrier.
//  - K granule pw: loaded by producer pw, read only by producer pw.
//    V slice pw: loaded by consumer pw, read only by consumer pw.
//    => per-wave counted vmcnt(8) after issuing the next 8 DMAs
//    guarantees the previous interval's 8 DMAs have landed (FIFO vmcnt).
// ---------------------------------------------------------------------------
__global__ __launch_bounds__(512, 2) void flash_attn(
    const short* __restrict__ qg, const short* __restrict__ kt,
    const short* __restrict__ vt, float* __restrict__ out) {
  const int xg = blockIdx.x;
  const int b  = xg >> 1;
  const int n0 = (((xg & 1) << 5) + blockIdx.y) * 64;
  const int tid = threadIdx.x;
  const int w = tid >> 6, lane = tid & 63;
  const int g = lane >> 4, c16 = lane & 15;
  const bool prod = (w < 4);
  const int pw = w & 3;            // producer granule / consumer o-slice

  __shared__ short kb[2][16384];   // K dbuf: 64 keys x 256 o
  __shared__ short vb[2][16384];   // V dbuf: 64 m x 256 o (o-major rows)
  __shared__ short ps[2][64][72];  // P dbuf: 64 n x 64 m
  __shared__ float lsum[4][64];

  const short* ktb = kt + (size_t)b * N_ * O_;
  const short* vtb = vt + (size_t)b * N_ * O_;

  bf16x8 qf[4][8];
  float lrun[4] = {0.f, 0.f, 0.f, 0.f};
  f32x4 oacc[4][4];
#pragma unroll
  for (int i = 0; i < 4; ++i)
#pragma unroll
    for (int j = 0; j < 4; ++j) oacc[i][j] = (f32x4){0.f, 0.f, 0.f, 0.f};

  if (prod) {
    // Q fragments: 4 n-subtiles x 8 k-steps (B-operand: col=n, k=o)
#pragma unroll
    for (int nt = 0; nt < 4; ++nt) {
      const short* qrow =
          qg + (size_t)(b * N_ + n0 + nt * 16 + c16) * O_ + g * 8;
#pragma unroll
      for (int ko = 0; ko < 8; ++ko)
        qf[nt][ko] = *(const bf16x8*)(qrow + ko * 32);
    }
    // prologue: K(0) granule pw
    const short* src = ktb + (size_t)pw * 4096;
#pragma unroll
    for (int j = 0; j < 8; ++j)
      dma16(src + j * 512 + lane * 8, &kb[0][pw * 4096 + j * 512]);
  }
  __syncthreads();   // full drain once: Q frags + K(0) resident after this

  const int sw = (g ^ ((c16 >> 1) & 3)) * 8;   // K chunk swizzle (shorts)

  for (int i = 0; i <= NIT; ++i) {
    if (prod) {
      if (i < NIT) {
        if (i + 1 < NIT) {  // prefetch K(i+1) granule pw, then wait K(i)
          const short* src = ktb + (size_t)(4 * (i + 1) + pw) * 4096;
          short* dst = &kb[(i + 1) & 1][pw * 4096];
#pragma unroll
          for (int j = 0; j < 8; ++j)
            dma16(src + j * 512 + lane * 8, dst + j * 512);
          asm volatile("s_waitcnt vmcnt(8)" ::: "memory");
        } else {
          asm volatile("s_waitcnt vmcnt(0)" ::: "memory");
        }
        __builtin_amdgcn_sched_barrier(0);
        // S^T = K Q^T for granule pw (rows m), all 64 n
        const short* ksl = &kb[i & 1][pw * 4096];
        f32x4 sacc[4];
#pragma unroll
        for (int nt = 0; nt < 4; ++nt) sacc[nt] = (f32x4){0.f, 0.f, 0.f, 0.f};
        __builtin_amdgcn_s_setprio(1);
#pragma unroll
        for (int ko = 0; ko < 8; ++ko) {
          bf16x8 kf = *(const bf16x8*)&ksl[(ko * 16 + c16) * 32 + sw];
#pragma unroll
          for (int nt = 0; nt < 4; ++nt)
            sacc[nt] = __builtin_amdgcn_mfma_f32_16x16x32_bf16(
                kf, qf[nt][ko], sacc[nt], 0, 0, 0);
        }
        __builtin_amdgcn_s_setprio(0);
        // p = exp(s) (no max subtraction: |s| <= ~2.5 by construction)
#pragma unroll
        for (int nt = 0; nt < 4; ++nt) {
          short4t pb;
          float rs = 0.f;
#pragma unroll
          for (int r = 0; r < 4; ++r) {
            float p = __expf(sacc[nt][r]);
            rs += p;
            pb[r] = f2bf(p);
          }
          lrun[nt] += rs;   // lane-local; folded over g at epilogue
          *(short4t*)&ps[i & 1][nt * 16 + c16][pw * 16 + g * 4] = pb;
        }
      }
      // i == NIT: producers idle (already drained to vmcnt(0) at NIT-1)
    } else {
      if (i < NIT) {  // prefetch V(i) o-slice pw
        const short* src = vtb + (size_t)i * 16384 + pw * 4096;
        short* dst = &vb[i & 1][pw * 4096];
#pragma unroll
        for (int j = 0; j < 8; ++j)
          dma16(src + j * 512 + lane * 8, dst + j * 512);
      }
      if (i > 0) {  // O += V(i-1) P(i-1)^T for o-slice pw
        if (i < NIT) {
          asm volatile("s_waitcnt vmcnt(8)" ::: "memory");  // V(i-1) landed
        } else {
          asm volatile("s_waitcnt vmcnt(0)" ::: "memory");
        }
        __builtin_amdgcn_sched_barrier(0);
        const int pb_ = (i - 1) & 1;
        __builtin_amdgcn_s_setprio(1);
#pragma unroll
        for (int kk = 0; kk < 2; ++kk) {
          bf16x8 pf[4];
#pragma unroll
          for (int nt = 0; nt < 4; ++nt)
            pf[nt] = *(const bf16x8*)&ps[pb_][nt * 16 + c16][kk * 32 + g * 8];
#pragma unroll
          for (int ot = 0; ot < 4; ++ot) {
            int pos = (kk * 4 + g) ^ (c16 & 7);
            bf16x8 vf = *(const bf16x8*)
                &vb[pb_][(pw * 64 + ot * 16 + c16) * 64 + pos * 8];
#pragma unroll
            for (int nt = 0; nt < 4; ++nt)
              oacc[ot][nt] = __builtin_amdgcn_mfma_f32_16x16x32_bf16(
                  vf, pf[nt], oacc[ot][nt], 0, 0, 0);
          }
        }
        __builtin_amdgcn_s_setprio(0);
      }
    }
    // ps handoff barrier: drain LDS ops only; DMAs stay in flight.
    asm volatile("s_waitcnt lgkmcnt(0)" ::: "memory");
    __builtin_amdgcn_s_barrier();
  }

  // epilogue: producers publish granule row-sums; consumers normalize+store
  if (prod) {
#pragma unroll
    for (int nt = 0; nt < 4; ++nt) {
      float v = lrun[nt];
      v += __shfl_xor(v, 16);
      v += __shfl_xor(v, 32);
      if (lane < 16) lsum[pw][nt * 16 + lane] = v;
    }
  }
  __syncthreads();
  if (!prod) {
#pragma unroll
    for (int nt = 0; nt < 4; ++nt) {
      const int nl = nt * 16 + c16;
      float l = lsum[0][nl] + lsum[1][nl] + lsum[2][nl] + lsum[3][nl];
      float li = 1.0f / l;
#pragma unroll
      for (int ot = 0; ot < 4; ++ot) {
        float* op = out + ((size_t)b * O_ + pw * 64 + ot * 16 + g * 4) * N_ +
                    n0 + nl;
#pragma unroll
        for (int r = 0; r < 4; ++r)
          op[(size_t)r * N_] = oacc[ot][nt][r] * li;
      }
    }
  }
}

// ---------------------------------------------------------------------------
extern "C" void kernel_launch(void* const* d_in, const int* in_sizes, int n_in,
                              void* d_out, int out_size, void* d_ws,
                              size_t ws_size, hipStream_t stream) {
  const float* x  = (const float*)d_in[0];
  const float* xx = (const float*)d_in[1];
  const float* Wq = (const float*)d_in[2];
  const float* Wk = (const float*)d_in[3];
  const float* Wv = (const float*)d_in[4];
  float* out = (float*)d_out;

  short* qg = (short*)d_ws;                         // 8.39 MB
  short* kt = qg + (size_t)B_ * N_ * O_;            // 8.39 MB (tiled K)
  short* vt = kt + (size_t)B_ * N_ * O_;            // 8.39 MB (tiled V)
  short* wb = vt + (size_t)B_ * N_ * O_;            // 384 KB

  wcvt<<<768, 256, 0, stream>>>(Wq, Wk, Wv, wb);
  qkv_proj<<<dim3(N_ / 64, B_, 3), 256, 0, stream>>>(x, xx, wb, qg, kt, vt);
  flash_attn<<<dim3(8, 32), 512, 0, stream>>>(qg, kt, vt, out);
}